// Round 17
// baseline (1884.057 us; speedup 1.0000x reference)
//
#include <hip/hip_runtime.h>
#include <math.h>

#define NB 16384
#define NT 10

typedef _Float16 f16;
typedef f16 f16x8 __attribute__((ext_vector_type(8)));
typedef f16 f16x4 __attribute__((ext_vector_type(4)));
typedef float f32x4 __attribute__((ext_vector_type(4)));

__device__ __forceinline__ float sigm_mid(float v) { return 1.0f / (1.0f + __expf(-v)); }
__device__ __forceinline__ float tanh_mid(float v) { return 1.0f - 2.0f / (1.0f + __expf(2.0f * v)); }
__device__ __forceinline__ float sigm_fast(float v) {
    return __builtin_amdgcn_rcpf(1.0f + __expf(-v));
}
__device__ __forceinline__ float tanh_fast(float v) {
    return 1.0f - 2.0f * __builtin_amdgcn_rcpf(1.0f + __expf(2.0f * v));
}

// async global->LDS, 16B per lane; lds dst is wave-uniform base (+lane*16 implicit)
__device__ __forceinline__ void async_cp16(const f16* g, f16* l) {
    __builtin_amdgcn_global_load_lds(
        (const __attribute__((address_space(1))) unsigned int*)g,
        (__attribute__((address_space(3))) unsigned int*)l, 16, 0, 0);
}

// ---------------- weight split: W (rows x kstride) -> hi/lo fp16 in [kg][rows][8] ----------------
__global__ __launch_bounds__(256) void wsplit_kernel(
    const float* __restrict__ W, f16* __restrict__ whi, f16* __restrict__ wlo,
    int rows, int kstride)
{
    const int u = blockIdx.x * 256 + threadIdx.x;
    const int kg = u / rows, row = u - kg * rows;
    const float* s = W + (size_t)row * kstride + kg * 8;
    f16x8 hi8, lo8;
    #pragma unroll
    for (int i = 0; i < 8; ++i) {
        float v = s[i];
        f16 hv = (f16)v;
        hi8[i] = hv;
        lo8[i] = (f16)(v - (float)hv);
    }
    *(f16x8*)&whi[(size_t)u * 8] = hi8;
    *(f16x8*)&wlo[(size_t)u * 8] = lo8;
}

// ---------------- feats split: x[:,16:272] -> hi/lo fp16 in [32 kg][NB][8] ----------------
__global__ __launch_bounds__(256) void xsplit_kernel(
    const float* __restrict__ x, f16* __restrict__ xhi, f16* __restrict__ xlo)
{
    const int u = blockIdx.x * 256 + threadIdx.x;
    const int kg = u >> 14, row = u & (NB - 1);
    const float* s = x + (size_t)row * 272 + 16 + kg * 8;
    f16x8 hi8, lo8;
    #pragma unroll
    for (int i = 0; i < 8; ++i) {
        float v = s[i];
        f16 hv = (f16)v;
        hi8[i] = hv;
        lo8[i] = (f16)(v - (float)hv);
    }
    *(f16x8*)&xhi[(size_t)u * 8] = hi8;
    *(f16x8*)&xlo[(size_t)u * 8] = lo8;
}

// ---------------- Wih transpose -> [128][1536] fp32 ----------------
__global__ __launch_bounds__(256) void wihT_kernel(
    const float* __restrict__ Wih, float* __restrict__ WihT)
{
    const int u = blockIdx.x * 256 + threadIdx.x;
    const int w = u / 1536, c = u - w * 1536;
    WihT[u] = Wih[(size_t)c * 128 + w];
}

// ---------------- h0 = tanh(feats @ W_in^T + b_in) via split MFMA, full NB ----------------
// A (feats) DMA double-buffer; B (W_in) direct global->reg (L2-hot).
__global__ __launch_bounds__(256, 2) void h0_mfma(
    const f16* __restrict__ xs_hi, const f16* __restrict__ xs_lo,
    const f16* __restrict__ win_hi, const f16* __restrict__ win_lo,
    const float* __restrict__ bias, f16* __restrict__ h_hi, f16* __restrict__ h_lo)
{
    constexpr int UNITS = 1024;   // Ah[4][128] | Al[4][128]
    __shared__ __align__(16) f16 lds[2 * UNITS * 8];
    const int t = threadIdx.x;
    const int lane = t & 63, wave = t >> 6;
    const int wm = wave >> 1, wn = wave & 1;
    const int nid = (blockIdx.x & 7) * 128 + (blockIdx.x >> 3);
    const int m0 = (nid >> 3) * 128;
    const int n0 = (nid & 7) * 64;
    const int wbase = t & 192;

    const f32x4 z4 = {0.f, 0.f, 0.f, 0.f};
    f32x4 acc[4][2];
    #pragma unroll
    for (int mi = 0; mi < 4; ++mi)
        #pragma unroll
        for (int ni = 0; ni < 2; ++ni) acc[mi][ni] = z4;

    const int asel = ((lane >> 4) << 7) + wm * 64 + (lane & 15);
    const size_t boff = ((size_t)(lane >> 4) * 512 + n0 + wn * 32 + (lane & 15)) * 8;
    const f16* bph = win_hi + boff;
    const f16* bpl = win_lo + boff;

    const f16* sp[4];
    #pragma unroll
    for (int i = 0; i < 4; ++i) {
        const int u = i * 256 + t;
        const int v = u & 511;
        const f16* hp = (u < 512) ? xs_hi : xs_lo;
        sp[i] = hp + ((size_t)(v >> 7) * NB + m0 + (v & 127)) * 8;
    }

    #define H0_STAGE(buf_) { \
        f16* lb_ = lds + ((size_t)(buf_) * UNITS + wbase) * 8; \
        _Pragma("unroll") \
        for (int i = 0; i < 4; ++i) { \
            async_cp16(sp[i], lb_ + (size_t)i * 256 * 8); \
            sp[i] += (size_t)NB * 32; \
        } \
    }

    H0_STAGE(0);
    asm volatile("s_waitcnt vmcnt(0)" ::: "memory");
    __syncthreads();

    for (int kb = 0; kb < 8; ++kb) {
        if (kb < 7) H0_STAGE((kb + 1) & 1);

        const f16* lb = lds + (size_t)(kb & 1) * UNITS * 8;
        f16x8 ah[4], al[4];
        #pragma unroll
        for (int mi = 0; mi < 4; ++mi) {
            ah[mi] = *(const f16x8*)&lb[(size_t)(asel + mi * 16) * 8];
            al[mi] = *(const f16x8*)&lb[(size_t)(512 + asel + mi * 16) * 8];
        }
        f16x8 bh[2], bl[2];
        #pragma unroll
        for (int ni = 0; ni < 2; ++ni) {
            bh[ni] = *(const f16x8*)(bph + (size_t)ni * 128);
            bl[ni] = *(const f16x8*)(bpl + (size_t)ni * 128);
        }
        bph += (size_t)4 * 512 * 8;
        bpl += (size_t)4 * 512 * 8;
        #pragma unroll
        for (int mi = 0; mi < 4; ++mi)
            #pragma unroll
            for (int ni = 0; ni < 2; ++ni) {
                acc[mi][ni] = __builtin_amdgcn_mfma_f32_16x16x32_f16(ah[mi], bh[ni], acc[mi][ni], 0, 0, 0);
                acc[mi][ni] = __builtin_amdgcn_mfma_f32_16x16x32_f16(ah[mi], bl[ni], acc[mi][ni], 0, 0, 0);
                acc[mi][ni] = __builtin_amdgcn_mfma_f32_16x16x32_f16(al[mi], bh[ni], acc[mi][ni], 0, 0, 0);
            }
        __syncthreads();
    }

    const int colb = n0 + wn * 32 + (lane & 15);
    const int rowb = m0 + wm * 64 + ((lane >> 4) << 2);
    #pragma unroll
    for (int ni = 0; ni < 2; ++ni) {
        const int col = colb + ni * 16;
        const float bb = bias[col];
        const size_t cbase = (size_t)(col >> 3) * NB * 8 + (col & 7);
        #pragma unroll
        for (int mi = 0; mi < 4; ++mi) {
            #pragma unroll
            for (int j = 0; j < 4; ++j) {
                const int r = rowb + mi * 16 + j;
                const float o = tanhf(acc[mi][ni][j] + bb);
                const f16 hh = (f16)o;
                const size_t idx = cbase + (size_t)r * 8;
                h_hi[idx] = hh;
                h_lo[idx] = (f16)(o - (float)hh);
            }
        }
    }
}

// A-staging pointer init (h slots only; textual inline — no lambda, R7-R9 scratch bug)
#define INIT_SP() { \
    _Pragma("unroll") \
    for (int i = 0; i < NST; ++i) { \
        const int u = i * 256 + t; \
        const f16* hp; int v; \
        if (PURE) { hp = hc_hi; v = u; } \
        else { v = u & 511; hp = (u < 512) ? hc_hi : hc_lo; } \
        sp[i] = hp + ((size_t)(v >> 7) * NB + m0 + (v & 127)) * 8; \
    } \
}
// DMA-stage one A K-block into lds buffer buf_ + advance (strength-reduced)
#define STAGE(buf_) { \
    f16* lb_ = lds + ((size_t)(buf_) * UNITS + wbase) * 8; \
    _Pragma("unroll") \
    for (int i = 0; i < NST; ++i) { \
        async_cp16(sp[i], lb_ + (size_t)i * 256 * 8); \
        sp[i] += (size_t)NB * 32; \
    } \
}

// ---------------- fused GRU step: A via DMA dbuf LDS, B direct global->reg, gates fused ----------------
// 1-D grid 1024 blocks, XCD-swizzled. block 256 (4 waves 2x2; wave tile 64r x 32c x 3 gates).
template <int HZERO, int PURE>
__global__ __launch_bounds__(256, 2) void fused_gru(
    const f16* __restrict__ hc_hi, const f16* __restrict__ hc_lo,
    f16* __restrict__ hn_hi, f16* __restrict__ hn_lo,
    const f16* __restrict__ w_hi, const f16* __restrict__ w_lo,
    const float* __restrict__ WihT,
    const float* __restrict__ bih, const float* __restrict__ bhh,
    const int* __restrict__ wsel)
{
    constexpr int UNITS = PURE ? 512 : 1024;   // A tiles only (16B units per buffer)
    constexpr int NST = PURE ? 2 : 4;
    __shared__ __align__(16) f16 lds[2 * UNITS * 8];
    const int t = threadIdx.x;
    const int lane = t & 63, wave = t >> 6;
    const int wm = wave >> 1, wn = wave & 1;
    const int nid = (blockIdx.x & 7) * 128 + (blockIdx.x >> 3);
    const int m0 = (nid >> 3) * 128;
    const int n0 = (nid & 7) * 64;
    const int wbase = t & 192;

    const f32x4 z4 = {0.f, 0.f, 0.f, 0.f};
    f32x4 acc[3][4][2];
    #pragma unroll
    for (int g = 0; g < 3; ++g)
        #pragma unroll
        for (int mi = 0; mi < 4; ++mi)
            #pragma unroll
            for (int ni = 0; ni < 2; ++ni) acc[g][mi][ni] = z4;

    float hold[2][4][4];
    #pragma unroll
    for (int ni = 0; ni < 2; ++ni)
        #pragma unroll
        for (int mi = 0; mi < 4; ++mi)
            #pragma unroll
            for (int j = 0; j < 4; ++j) hold[ni][mi][j] = 0.f;

    if (!HZERO) {
        const int asel = ((lane >> 4) << 7) + wm * 64 + (lane & 15);
        // B direct-to-reg base (per lane): w[(lane>>4)*1536 + n0 + wn*32 + (lane&15)], frag offs (g*512+ni*16)*8
        const size_t boff = ((size_t)(lane >> 4) * 1536 + n0 + wn * 32 + (lane & 15)) * 8;
        const f16* bph = w_hi + boff;
        const f16* bpl = PURE ? (const f16*)nullptr : (w_lo + boff);
        // hold-capture coordinates (from LDS A-tile at iteration kbE)
        const int kbE = (n0 >> 5) + wn;
        const int kglA = (lane & 15) >> 3;
        const int rowlA = wm * 64 + ((lane >> 4) << 2);
        const int elemA = lane & 7;

        const f16* sp[NST];
        INIT_SP();
        STAGE(0);
        asm volatile("s_waitcnt vmcnt(0)" ::: "memory");
        __syncthreads();

        for (int kb = 0; kb < 16; ++kb) {
            if (kb < 15) STAGE((kb + 1) & 1);   // A DMA into other buffer, lands under MFMA

            const f16* lb = lds + (size_t)(kb & 1) * UNITS * 8;
            f16x8 ah[4], al[4];
            #pragma unroll
            for (int mi = 0; mi < 4; ++mi) {
                ah[mi] = *(const f16x8*)&lb[(size_t)(asel + mi * 16) * 8];
                if (!PURE) al[mi] = *(const f16x8*)&lb[(size_t)(512 + asel + mi * 16) * 8];
            }
            #pragma unroll
            for (int g = 0; g < 3; ++g) {
                f16x8 bh[2], bl[2];
                #pragma unroll
                for (int ni = 0; ni < 2; ++ni) {
                    bh[ni] = *(const f16x8*)(bph + (size_t)(g * 512 + ni * 16) * 8);
                    if (!PURE) bl[ni] = *(const f16x8*)(bpl + (size_t)(g * 512 + ni * 16) * 8);
                }
                #pragma unroll
                for (int mi = 0; mi < 4; ++mi)
                    #pragma unroll
                    for (int ni = 0; ni < 2; ++ni) {
                        acc[g][mi][ni] = __builtin_amdgcn_mfma_f32_16x16x32_f16(ah[mi], bh[ni], acc[g][mi][ni], 0, 0, 0);
                        if (!PURE) {
                            acc[g][mi][ni] = __builtin_amdgcn_mfma_f32_16x16x32_f16(ah[mi], bl[ni], acc[g][mi][ni], 0, 0, 0);
                            acc[g][mi][ni] = __builtin_amdgcn_mfma_f32_16x16x32_f16(al[mi], bh[ni], acc[g][mi][ni], 0, 0, 0);
                        }
                    }
            }
            bph += (size_t)4 * 1536 * 8;
            if (!PURE) bpl += (size_t)4 * 1536 * 8;

            if (kb == kbE) {   // capture h_old from A-tile (wave-uniform branch)
                #pragma unroll
                for (int ni = 0; ni < 2; ++ni)
                    #pragma unroll
                    for (int mi = 0; mi < 4; ++mi)
                        #pragma unroll
                        for (int j = 0; j < 4; ++j) {
                            const int unit = (kglA + 2 * ni) * 128 + rowlA + mi * 16 + j;
                            float hv = (float)lb[(size_t)unit * 8 + elemA];
                            if (!PURE) hv += (float)lb[(size_t)(512 + unit) * 8 + elemA];
                            hold[ni][mi][j] = hv;
                        }
            }
            __syncthreads();   // drains vmcnt: A DMA for next buf complete
        }
    }

    // ---- epilogue: GRU gate math in-register, write h_next ----
    const int colb = n0 + wn * 32 + (lane & 15);
    const int rowb = m0 + wm * 64 + ((lane >> 4) << 2);
    int wd[16];
    if (wsel) {
        #pragma unroll
        for (int mi = 0; mi < 4; ++mi) {
            const int4 w4 = *(const int4*)&wsel[rowb + mi * 16];
            wd[mi * 4 + 0] = w4.x; wd[mi * 4 + 1] = w4.y;
            wd[mi * 4 + 2] = w4.z; wd[mi * 4 + 3] = w4.w;
        }
    } else {
        #pragma unroll
        for (int i = 0; i < 16; ++i) wd[i] = -1;
    }

    #pragma unroll
    for (int ni = 0; ni < 2; ++ni) {
        const int col = colb + ni * 16;
        const float b_r = bih[col], b_z = bih[512 + col], b_n = bih[1024 + col];
        const float c_r = bhh[col], c_z = bhh[512 + col], c_n = bhh[1024 + col];
        const size_t cbase = (size_t)(col >> 3) * NB * 8 + (col & 7);
        #pragma unroll
        for (int mi = 0; mi < 4; ++mi) {
            #pragma unroll
            for (int j = 0; j < 4; ++j) {
                const int r = rowb + mi * 16 + j;
                const int word = wd[mi * 4 + j];
                float wir = 0.f, wiz = 0.f, win = 0.f;
                if (word >= 0) {
                    const float* wt = WihT + (size_t)word * 1536 + col;
                    wir = wt[0]; wiz = wt[512]; win = wt[1024];
                }
                const size_t idx = cbase + (size_t)r * 8;
                const float ra = wir + b_r + acc[0][mi][ni][j] + c_r;
                const float za = wiz + b_z + acc[1][mi][ni][j] + c_z;
                const float rr = PURE ? sigm_fast(ra) : sigm_mid(ra);
                const float zz = PURE ? sigm_fast(za) : sigm_mid(za);
                const float na = win + b_n + rr * (acc[2][mi][ni][j] + c_n);
                const float nn = PURE ? tanh_fast(na) : tanh_mid(na);
                const float hv = (1.f - zz) * nn + zz * hold[ni][mi][j];
                const f16 hh = (f16)hv;
                hn_hi[idx] = hh;
                if (!PURE) hn_lo[idx] = (f16)(hv - (float)hh);
            }
        }
    }
}

// ---------------- logits+gumbel argmax: A via DMA dbuf, B (Wsp) direct global->reg ----------------
// grid NB/64 = 256, block 256 (4 waves; wave = 16 rows x all 128 cols)
__global__ __launch_bounds__(256, 2) void argmax_mfma(
    const f16* __restrict__ h_hi, const f16* __restrict__ h_lo,
    const f16* __restrict__ wsp_hi, const f16* __restrict__ wsp_lo,
    const float* __restrict__ bsp, const float* __restrict__ gum,
    int* __restrict__ wout)
{
    constexpr int UNITS = 512;   // Ah[4][64] | Al[4][64]
    __shared__ __align__(16) f16 lds[2 * UNITS * 8];
    const int t = threadIdx.x;
    const int lane = t & 63, wave = t >> 6;
    const int mBase = blockIdx.x * 64;
    const int wbase = t & 192;

    const f32x4 z4 = {0.f, 0.f, 0.f, 0.f};
    f32x4 acc[8];
    #pragma unroll
    for (int nf = 0; nf < 8; ++nf) acc[nf] = z4;

    const f16* sp[2];
    sp[0] = h_hi + ((size_t)(t >> 6) * NB + mBase + (t & 63)) * 8;
    sp[1] = h_lo + ((size_t)(t >> 6) * NB + mBase + (t & 63)) * 8;

    const size_t boff = ((size_t)(lane >> 4) * 128 + (lane & 15)) * 8;
    const f16* bph = wsp_hi + boff;
    const f16* bpl = wsp_lo + boff;

    #define AM_STAGE(buf_) { \
        f16* lb_ = lds + ((size_t)(buf_) * UNITS + wbase) * 8; \
        async_cp16(sp[0], lb_); \
        async_cp16(sp[1], lb_ + (size_t)256 * 8); \
        sp[0] += (size_t)NB * 32; \
        sp[1] += (size_t)NB * 32; \
    }

    AM_STAGE(0);
    asm volatile("s_waitcnt vmcnt(0)" ::: "memory");
    __syncthreads();

    const int aselU = (lane >> 4) * 64 + wave * 16 + (lane & 15);

    for (int kb = 0; kb < 16; ++kb) {
        if (kb < 15) AM_STAGE((kb + 1) & 1);

        const f16* lb = lds + (size_t)(kb & 1) * UNITS * 8;
        f16x8 ah = *(const f16x8*)&lb[(size_t)aselU * 8];
        f16x8 al = *(const f16x8*)&lb[(size_t)(256 + aselU) * 8];
        #pragma unroll
        for (int nf = 0; nf < 8; ++nf) {
            f16x8 bh = *(const f16x8*)(bph + (size_t)nf * 128);
            f16x8 bl = *(const f16x8*)(bpl + (size_t)nf * 128);
            acc[nf] = __builtin_amdgcn_mfma_f32_16x16x32_f16(ah, bh, acc[nf], 0, 0, 0);
            acc[nf] = __builtin_amdgcn_mfma_f32_16x16x32_f16(ah, bl, acc[nf], 0, 0, 0);
            acc[nf] = __builtin_amdgcn_mfma_f32_16x16x32_f16(al, bh, acc[nf], 0, 0, 0);
        }
        bph += (size_t)4 * 128 * 8;
        bpl += (size_t)4 * 128 * 8;
        __syncthreads();
    }

    float bv[4];
    int bi[4];
    #pragma unroll
    for (int j = 0; j < 4; ++j) { bv[j] = -1e30f; bi[j] = 0; }
    const int rw0 = mBase + wave * 16 + ((lane >> 4) << 2);
    #pragma unroll
    for (int nf = 0; nf < 8; ++nf) {
        const int col = (lane & 15) + nf * 16;
        const float bb = bsp[col];
        #pragma unroll
        for (int j = 0; j < 4; ++j) {
            const float v = acc[nf][j] + bb + gum[(size_t)(rw0 + j) * 128 + col];
            if (v > bv[j] || (v == bv[j] && col < bi[j])) { bv[j] = v; bi[j] = col; }
        }
    }
    #pragma unroll
    for (int j = 0; j < 4; ++j) {
        #pragma unroll
        for (int off = 1; off <= 8; off <<= 1) {
            const float ov = __shfl_xor(bv[j], off, 64);
            const int oi = __shfl_xor(bi[j], off, 64);
            if (ov > bv[j] || (ov == bv[j] && oi < bi[j])) { bv[j] = ov; bi[j] = oi; }
        }
        if ((lane & 15) == 0) wout[rw0 + j] = bi[j];
    }
}

// ---------------- alive mask -> effective word (-1 = zero input) ----------------
__global__ __launch_bounds__(256) void eff_kernel(
    const int* __restrict__ words, int* __restrict__ eff)
{
    const int b = blockIdx.x * 256 + threadIdx.x;
    int alive = 1;
    #pragma unroll
    for (int t = 0; t < NT; ++t) {
        const int w = words[(size_t)t * NB + b];
        eff[(size_t)t * NB + b] = alive ? w : -1;
        alive = alive & (w != 0);
    }
}

// ---------------- score = [h_n, task] @ W_c^T + b_c (full NB, hi-only state) ----------------
__global__ __launch_bounds__(256) void score_kernel(
    const f16* __restrict__ h_hi,
    const float* __restrict__ x, const float* __restrict__ Wc,
    const float* __restrict__ bc, float* __restrict__ out)
{
    __shared__ float Wcs[10][528];
    const int t = threadIdx.x;
    for (int q = t; q < 1320; q += 256)
        *(float4*)&(((float*)Wcs)[q * 4]) = *(const float4*)&Wc[q * 4];
    __syncthreads();

    const int row = blockIdx.x * 256 + t;
    float acc[10];
    #pragma unroll
    for (int d = 0; d < 10; ++d) acc[d] = 0.f;

    for (int kg = 0; kg < 64; ++kg) {
        f16x8 vh = *(const f16x8*)&h_hi[((size_t)kg * NB + row) * 8];
        #pragma unroll
        for (int i = 0; i < 8; ++i) {
            const float v = (float)vh[i];
            #pragma unroll
            for (int d = 0; d < 10; ++d) acc[d] += v * Wcs[d][kg * 8 + i];
        }
    }
    #pragma unroll
    for (int j = 0; j < 16; ++j) {
        const float tv = x[(size_t)row * 272 + j];
        #pragma unroll
        for (int d = 0; d < 10; ++d) acc[d] += tv * Wcs[d][512 + j];
    }
    #pragma unroll
    for (int d = 0; d < 10; ++d) out[(size_t)row * 10 + d] = acc[d] + bc[d];
}

extern "C" void kernel_launch(void* const* d_in, const int* in_sizes, int n_in,
                              void* d_out, int out_size, void* d_ws, size_t ws_size,
                              hipStream_t stream) {
    const float* x      = (const float*)d_in[0];
    const float* gumbel = (const float*)d_in[1];
    const float* W_in   = (const float*)d_in[2];
    const float* b_in   = (const float*)d_in[3];
    const float* Wih_s  = (const float*)d_in[4];
    const float* Whh_s  = (const float*)d_in[5];
    const float* bih_s  = (const float*)d_in[6];
    const float* bhh_s  = (const float*)d_in[7];
    const float* W_sp   = (const float*)d_in[8];
    const float* b_sp   = (const float*)d_in[9];
    const float* Wih_r  = (const float*)d_in[10];
    const float* Whh_r  = (const float*)d_in[11];
    const float* bih_r  = (const float*)d_in[12];
    const float* bhh_r  = (const float*)d_in[13];
    const float* W_c    = (const float*)d_in[14];
    const float* b_c    = (const float*)d_in[15];
    float* out = (float*)d_out;

    // workspace map (bytes), total ~94 MB (ws = 320 MiB per harness poison fill)
    char* base = (char*)d_ws;
    f16* S_hi[2], *S_lo[2];
    S_hi[0] = (f16*)(base);
    S_lo[0] = (f16*)(base + 16777216);
    S_hi[1] = (f16*)(base + 33554432);
    S_lo[1] = (f16*)(base + 50331648);
    f16* R0 = (f16*)(base);
    f16* R1 = (f16*)(base + 16777216);
    f16* ws_s_hi = (f16*)(base + 67108864);
    f16* ws_s_lo = (f16*)(base + 68681728);
    f16* ws_r_hi = (f16*)(base + 70254592);
    f16* ws_r_lo = (f16*)(base + 71827456);
    float* wihT_s = (float*)(base + 73400320);
    float* wihT_r = (float*)(base + 74186752);
    int* words   = (int*)(base + 74973184);
    int* eff     = (int*)(base + 75628544);
    f16* wsp_hi  = (f16*)(base + 76283904);
    f16* wsp_lo  = (f16*)(base + 76414976);
    f16* xs_hi   = (f16*)(base + 76546048);
    f16* xs_lo   = (f16*)(base + 84934656);
    f16* win_hi  = (f16*)(base + 93323264);
    f16* win_lo  = (f16*)(base + 93585408);

    const dim3 blk(256);
    const dim3 gFus(NB / 128 * 8);    // 1024 blocks, 1-D, XCD-swizzled in-kernel

    // ---- weight/input prep ----
    wsplit_kernel<<<dim3(384), blk, 0, stream>>>(Whh_s, ws_s_hi, ws_s_lo, 1536, 512);
    wsplit_kernel<<<dim3(384), blk, 0, stream>>>(Whh_r, ws_r_hi, ws_r_lo, 1536, 512);
    wsplit_kernel<<<dim3(32), blk, 0, stream>>>(W_sp, wsp_hi, wsp_lo, 128, 512);
    wsplit_kernel<<<dim3(64), blk, 0, stream>>>(W_in, win_hi, win_lo, 512, 256);
    xsplit_kernel<<<dim3(2048), blk, 0, stream>>>(x, xs_hi, xs_lo);
    wihT_kernel<<<dim3(768), blk, 0, stream>>>(Wih_s, wihT_s);
    wihT_kernel<<<dim3(768), blk, 0, stream>>>(Wih_r, wihT_r);

    // ---- h0 into S0 (full NB, split MFMA) ----
    h0_mfma<<<gFus, blk, 0, stream>>>(xs_hi, xs_lo, win_hi, win_lo, b_in, S_hi[0], S_lo[0]);
    int cur = 0;

    // ---- sender: 10 fused GRU steps (split, triple-product) + MFMA argmax ----
    for (int t = 0; t < NT; ++t) {
        const int* wprev = (t == 0) ? (const int*)nullptr : (words + (size_t)(t - 1) * NB);
        const int nxt = cur ^ 1;
        fused_gru<0, 0><<<gFus, blk, 0, stream>>>(
            S_hi[cur], S_lo[cur], S_hi[nxt], S_lo[nxt],
            ws_s_hi, ws_s_lo, wihT_s, bih_s, bhh_s, wprev);
        cur = nxt;
        argmax_mfma<<<dim3(NB / 64), blk, 0, stream>>>(
            S_hi[cur], S_lo[cur], wsp_hi, wsp_lo,
            b_sp, gumbel + (size_t)t * NB * 128, words + (size_t)t * NB);
    }
    eff_kernel<<<dim3(NB / 256), blk, 0, stream>>>(words, eff);

    // ---- receiver: 10 fused GRU steps, pure fp16 hi-only, full-NB ping-pong ----
    fused_gru<1, 1><<<gFus, blk, 0, stream>>>(
        R1, R1, R0, R0, ws_r_hi, ws_r_lo, wihT_r, bih_r, bhh_r, eff);
    for (int t = 1; t < NT; ++t) {
        f16* rin  = (t & 1) ? R0 : R1;
        f16* rout = (t & 1) ? R1 : R0;
        fused_gru<0, 1><<<gFus, blk, 0, stream>>>(
            rin, rin, rout, rout, ws_r_hi, ws_r_lo, wihT_r, bih_r, bhh_r,
            eff + (size_t)t * NB);
    }

    // ---- score (final receiver state in R1: t=9 is odd) ----
    score_kernel<<<dim3(NB / 256), blk, 0, stream>>>(R1, x, W_c, b_c, out);
}

// Round 18
// 1452.467 us; speedup vs baseline: 1.2971x; 1.2971x over previous
//
#include <hip/hip_runtime.h>
#include <math.h>

#define NB 16384
#define NT 10

typedef _Float16 f16;
typedef f16 f16x8 __attribute__((ext_vector_type(8)));
typedef f16 f16x4 __attribute__((ext_vector_type(4)));
typedef float f32x4 __attribute__((ext_vector_type(4)));

__device__ __forceinline__ float sigm_mid(float v) { return 1.0f / (1.0f + __expf(-v)); }
__device__ __forceinline__ float tanh_mid(float v) { return 1.0f - 2.0f / (1.0f + __expf(2.0f * v)); }
__device__ __forceinline__ float sigm_fast(float v) {
    return __builtin_amdgcn_rcpf(1.0f + __expf(-v));
}
__device__ __forceinline__ float tanh_fast(float v) {
    return 1.0f - 2.0f * __builtin_amdgcn_rcpf(1.0f + __expf(2.0f * v));
}

// async global->LDS, 16B per lane; lds dst is wave-uniform base (+lane*16 implicit)
__device__ __forceinline__ void async_cp16(const f16* g, f16* l) {
    __builtin_amdgcn_global_load_lds(
        (const __attribute__((address_space(1))) unsigned int*)g,
        (__attribute__((address_space(3))) unsigned int*)l, 16, 0, 0);
}

// ---------------- weight split: W (rows x kstride) -> hi/lo fp16 in [kg][rows][8] ----------------
__global__ __launch_bounds__(256) void wsplit_kernel(
    const float* __restrict__ W, f16* __restrict__ whi, f16* __restrict__ wlo,
    int rows, int kstride)
{
    const int u = blockIdx.x * 256 + threadIdx.x;
    const int kg = u / rows, row = u - kg * rows;
    const float* s = W + (size_t)row * kstride + kg * 8;
    f16x8 hi8, lo8;
    #pragma unroll
    for (int i = 0; i < 8; ++i) {
        float v = s[i];
        f16 hv = (f16)v;
        hi8[i] = hv;
        lo8[i] = (f16)(v - (float)hv);
    }
    *(f16x8*)&whi[(size_t)u * 8] = hi8;
    *(f16x8*)&wlo[(size_t)u * 8] = lo8;
}

// ---------------- feats split: x[:,16:272] -> hi/lo fp16 in [32 kg][NB][8] ----------------
__global__ __launch_bounds__(256) void xsplit_kernel(
    const float* __restrict__ x, f16* __restrict__ xhi, f16* __restrict__ xlo)
{
    const int u = blockIdx.x * 256 + threadIdx.x;
    const int kg = u >> 14, row = u & (NB - 1);
    const float* s = x + (size_t)row * 272 + 16 + kg * 8;
    f16x8 hi8, lo8;
    #pragma unroll
    for (int i = 0; i < 8; ++i) {
        float v = s[i];
        f16 hv = (f16)v;
        hi8[i] = hv;
        lo8[i] = (f16)(v - (float)hv);
    }
    *(f16x8*)&xhi[(size_t)u * 8] = hi8;
    *(f16x8*)&xlo[(size_t)u * 8] = lo8;
}

// ---------------- Wih transpose -> [128][1536] fp32 ----------------
__global__ __launch_bounds__(256) void wihT_kernel(
    const float* __restrict__ Wih, float* __restrict__ WihT)
{
    const int u = blockIdx.x * 256 + threadIdx.x;
    const int w = u / 1536, c = u - w * 1536;
    WihT[u] = Wih[(size_t)c * 128 + w];
}

// ---------------- h0 = tanh(feats @ W_in^T + b_in) via split MFMA, full NB ----------------
__global__ __launch_bounds__(256, 2) void h0_mfma(
    const f16* __restrict__ xs_hi, const f16* __restrict__ xs_lo,
    const f16* __restrict__ win_hi, const f16* __restrict__ win_lo,
    const float* __restrict__ bias, f16* __restrict__ h_hi, f16* __restrict__ h_lo)
{
    constexpr int UNITS = 1536;
    __shared__ __align__(16) f16 lds[2 * UNITS * 8];
    const int t = threadIdx.x;
    const int lane = t & 63, wave = t >> 6;
    const int wm = wave >> 1, wn = wave & 1;
    const int nid = (blockIdx.x & 7) * 128 + (blockIdx.x >> 3);
    const int m0 = (nid >> 3) * 128;
    const int n0 = (nid & 7) * 64;
    const int wbase = t & 192;

    const f32x4 z4 = {0.f, 0.f, 0.f, 0.f};
    f32x4 acc[4][2];
    #pragma unroll
    for (int mi = 0; mi < 4; ++mi)
        #pragma unroll
        for (int ni = 0; ni < 2; ++ni) acc[mi][ni] = z4;

    const int asel = ((lane >> 4) << 7) + wm * 64 + (lane & 15);
    const int bsel = ((lane >> 4) << 6) + wn * 32 + (lane & 15);

    const f16* sp[6];
    #pragma unroll
    for (int i = 0; i < 6; ++i) {
        const int u = i * 256 + t;
        const f16* src;
        if (u < 512) {
            src = xs_hi + ((size_t)(u >> 7) * NB + m0 + (u & 127)) * 8;
        } else if (u < 1024) {
            const int v = u - 512;
            src = xs_lo + ((size_t)(v >> 7) * NB + m0 + (v & 127)) * 8;
        } else if (u < 1280) {
            const int v = u - 1024;
            src = win_hi + ((size_t)(v >> 6) * 512 + n0 + (v & 63)) * 8;
        } else {
            const int v = u - 1280;
            src = win_lo + ((size_t)(v >> 6) * 512 + n0 + (v & 63)) * 8;
        }
        sp[i] = src;
    }

    #define H0_STAGE(buf_) { \
        f16* lb_ = lds + ((size_t)(buf_) * UNITS + wbase) * 8; \
        _Pragma("unroll") \
        for (int i = 0; i < 6; ++i) { \
            async_cp16(sp[i], lb_ + (size_t)i * 256 * 8); \
            sp[i] += (i < 4) ? (size_t)NB * 32 : (size_t)16384; \
        } \
    }

    H0_STAGE(0);
    asm volatile("s_waitcnt vmcnt(0)" ::: "memory");
    __syncthreads();

    for (int kb = 0; kb < 8; ++kb) {
        if (kb < 7) H0_STAGE((kb + 1) & 1);

        const f16* lb = lds + (size_t)(kb & 1) * UNITS * 8;
        f16x8 ah[4], al[4];
        #pragma unroll
        for (int mi = 0; mi < 4; ++mi) {
            ah[mi] = *(const f16x8*)&lb[(size_t)(asel + mi * 16) * 8];
            al[mi] = *(const f16x8*)&lb[(size_t)(512 + asel + mi * 16) * 8];
        }
        f16x8 bh[2], bl[2];
        #pragma unroll
        for (int ni = 0; ni < 2; ++ni) {
            bh[ni] = *(const f16x8*)&lb[(size_t)(1024 + bsel + ni * 16) * 8];
            bl[ni] = *(const f16x8*)&lb[(size_t)(1280 + bsel + ni * 16) * 8];
        }
        #pragma unroll
        for (int mi = 0; mi < 4; ++mi)
            #pragma unroll
            for (int ni = 0; ni < 2; ++ni) {
                acc[mi][ni] = __builtin_amdgcn_mfma_f32_16x16x32_f16(ah[mi], bh[ni], acc[mi][ni], 0, 0, 0);
                acc[mi][ni] = __builtin_amdgcn_mfma_f32_16x16x32_f16(ah[mi], bl[ni], acc[mi][ni], 0, 0, 0);
                acc[mi][ni] = __builtin_amdgcn_mfma_f32_16x16x32_f16(al[mi], bh[ni], acc[mi][ni], 0, 0, 0);
            }
        __syncthreads();
    }

    const int colb = n0 + wn * 32 + (lane & 15);
    const int rowb = m0 + wm * 64 + ((lane >> 4) << 2);
    #pragma unroll
    for (int ni = 0; ni < 2; ++ni) {
        const int col = colb + ni * 16;
        const float bb = bias[col];
        const size_t cbase = (size_t)(col >> 3) * NB * 8 + (col & 7);
        #pragma unroll
        for (int mi = 0; mi < 4; ++mi) {
            #pragma unroll
            for (int j = 0; j < 4; ++j) {
                const int r = rowb + mi * 16 + j;
                const float o = tanhf(acc[mi][ni][j] + bb);
                const f16 hh = (f16)o;
                const size_t idx = cbase + (size_t)r * 8;
                h_hi[idx] = hh;
                h_lo[idx] = (f16)(o - (float)hh);
            }
        }
    }
}

// init per-slot staging pointers (textual inline; no lambda — R7-R9 scratch bug)
#define INIT_SP() { \
    _Pragma("unroll") \
    for (int i = 0; i < NST; ++i) { \
        const int u = i * 256 + t; \
        const f16* src; \
        if (PURE) { \
            if (u < 512) { \
                src = hc_hi + ((size_t)(u >> 7) * NB + m0 + (u & 127)) * 8; \
            } else { \
                const int w = u - 512; \
                src = w_hi + ((size_t)((w >> 6) & 3) * 1536 + (w >> 8) * 512 + n0 + (w & 63)) * 8; \
            } \
        } else { \
            if (u < 1024) { \
                const int v = u & 511; \
                const f16* hp = (u < 512) ? hc_hi : hc_lo; \
                src = hp + ((size_t)(v >> 7) * NB + m0 + (v & 127)) * 8; \
            } else { \
                const int v = u - 1024; \
                const f16* wp = (v < 768) ? w_hi : w_lo; \
                const int w = (v < 768) ? v : v - 768; \
                src = wp + ((size_t)((w >> 6) & 3) * 1536 + (w >> 8) * 512 + n0 + (w & 63)) * 8; \
            } \
        } \
        sp[i] = src; \
    } \
}
// DMA-stage one K-block into lds buffer buf_ + advance pointers (strength-reduced)
#define STAGE(buf_) { \
    f16* lb_ = lds + ((size_t)(buf_) * UNITS + wbase) * 8; \
    _Pragma("unroll") \
    for (int i = 0; i < NST; ++i) { \
        async_cp16(sp[i], lb_ + (size_t)i * 256 * 8); \
        sp[i] += (i < HCNT) ? (size_t)NB * 32 : (size_t)49152; \
    } \
}

// ---------------- fused GRU step: DMA-staged double-buffered split/pure MFMA GEMM + gates ----------------
// 1-D grid 1024 blocks, XCD-swizzled. block 256 (4 waves 2x2; wave tile 64r x 32c x 3 gates).
// h_old (epilogue) captured from the LDS A-tile at iteration kbE — no global re-read.
template <int HZERO, int PURE>
__global__ __launch_bounds__(256, 2) void fused_gru(
    const f16* __restrict__ hc_hi, const f16* __restrict__ hc_lo,
    f16* __restrict__ hn_hi, f16* __restrict__ hn_lo,
    const f16* __restrict__ w_hi, const f16* __restrict__ w_lo,
    const float* __restrict__ WihT,
    const float* __restrict__ bih, const float* __restrict__ bhh,
    const int* __restrict__ wsel)
{
    constexpr int UNITS = PURE ? 1280 : 2560;   // 16B units per buffer
    constexpr int NST = PURE ? 5 : 10;
    constexpr int HCNT = PURE ? 2 : 4;          // slots sourcing from h (stride NB*32)
    __shared__ __align__(16) f16 lds[2 * UNITS * 8];
    const int t = threadIdx.x;
    const int lane = t & 63, wave = t >> 6;
    const int wm = wave >> 1, wn = wave & 1;
    const int nid = (blockIdx.x & 7) * 128 + (blockIdx.x >> 3);
    const int m0 = (nid >> 3) * 128;
    const int n0 = (nid & 7) * 64;
    const int wbase = t & 192;   // wave*64 (wave-uniform LDS base for DMA)

    const f32x4 z4 = {0.f, 0.f, 0.f, 0.f};
    f32x4 acc[3][4][2];
    #pragma unroll
    for (int g = 0; g < 3; ++g)
        #pragma unroll
        for (int mi = 0; mi < 4; ++mi)
            #pragma unroll
            for (int ni = 0; ni < 2; ++ni) acc[g][mi][ni] = z4;

    // h_old registers, filled from LDS A-tile during the K-loop (zeros if HZERO)
    float hold[2][4][4];
    #pragma unroll
    for (int ni = 0; ni < 2; ++ni)
        #pragma unroll
        for (int mi = 0; mi < 4; ++mi)
            #pragma unroll
            for (int j = 0; j < 4; ++j) hold[ni][mi][j] = 0.f;

    if (!HZERO) {
        const int asel = ((lane >> 4) << 7) + wm * 64 + (lane & 15);
        const int bsel = ((lane >> 4) << 6) + wn * 32 + (lane & 15);
        constexpr int B0 = PURE ? 512 : 1024;   // B-hi base unit
        // iteration at which this wave's epilogue columns pass through the A-tile
        const int kbE = (n0 >> 5) + wn;
        const int kglA = (lane & 15) >> 3;            // + 2*ni
        const int rowlA = wm * 64 + ((lane >> 4) << 2); // + mi*16 + j
        const int elemA = lane & 7;

        const f16* sp[NST];
        INIT_SP();
        STAGE(0);
        asm volatile("s_waitcnt vmcnt(0)" ::: "memory");
        __syncthreads();

        for (int kb = 0; kb < 16; ++kb) {
            if (kb < 15) STAGE((kb + 1) & 1);   // DMA into other buffer, lands under MFMA

            const f16* lb = lds + (size_t)(kb & 1) * UNITS * 8;
            f16x8 ah[4], al[4];
            #pragma unroll
            for (int mi = 0; mi < 4; ++mi) {
                ah[mi] = *(const f16x8*)&lb[(size_t)(asel + mi * 16) * 8];
                if (!PURE) al[mi] = *(const f16x8*)&lb[(size_t)(512 + asel + mi * 16) * 8];
            }
            #pragma unroll
            for (int g = 0; g < 3; ++g) {
                f16x8 bh[2], bl[2];
                #pragma unroll
                for (int ni = 0; ni < 2; ++ni) {
                    bh[ni] = *(const f16x8*)&lb[(size_t)(B0 + g * 256 + bsel + ni * 16) * 8];
                    if (!PURE) bl[ni] = *(const f16x8*)&lb[(size_t)(1792 + g * 256 + bsel + ni * 16) * 8];
                }
                #pragma unroll
                for (int mi = 0; mi < 4; ++mi)
                    #pragma unroll
                    for (int ni = 0; ni < 2; ++ni) {
                        acc[g][mi][ni] = __builtin_amdgcn_mfma_f32_16x16x32_f16(ah[mi], bh[ni], acc[g][mi][ni], 0, 0, 0);
                        if (!PURE) {
                            acc[g][mi][ni] = __builtin_amdgcn_mfma_f32_16x16x32_f16(ah[mi], bl[ni], acc[g][mi][ni], 0, 0, 0);
                            acc[g][mi][ni] = __builtin_amdgcn_mfma_f32_16x16x32_f16(al[mi], bh[ni], acc[g][mi][ni], 0, 0, 0);
                        }
                    }
            }

            // capture h_old for the epilogue from the A-tile (wave-uniform branch)
            if (kb == kbE) {
                #pragma unroll
                for (int ni = 0; ni < 2; ++ni)
                    #pragma unroll
                    for (int mi = 0; mi < 4; ++mi)
                        #pragma unroll
                        for (int j = 0; j < 4; ++j) {
                            const int unit = (kglA + 2 * ni) * 128 + rowlA + mi * 16 + j;
                            float hv = (float)lb[(size_t)unit * 8 + elemA];
                            if (!PURE) hv += (float)lb[(size_t)(512 + unit) * 8 + elemA];
                            hold[ni][mi][j] = hv;
                        }
            }
            __syncthreads();   // drains vmcnt: DMA for next buf complete
        }
    }

    // ---- epilogue: GRU gate math in-register, write h_next ----
    const int colb = n0 + wn * 32 + (lane & 15);
    const int rowb = m0 + wm * 64 + ((lane >> 4) << 2);
    int wd[16];
    if (wsel) {
        #pragma unroll
        for (int mi = 0; mi < 4; ++mi) {
            const int4 w4 = *(const int4*)&wsel[rowb + mi * 16];
            wd[mi * 4 + 0] = w4.x; wd[mi * 4 + 1] = w4.y;
            wd[mi * 4 + 2] = w4.z; wd[mi * 4 + 3] = w4.w;
        }
    } else {
        #pragma unroll
        for (int i = 0; i < 16; ++i) wd[i] = -1;
    }

    #pragma unroll
    for (int ni = 0; ni < 2; ++ni) {
        const int col = colb + ni * 16;
        const float b_r = bih[col], b_z = bih[512 + col], b_n = bih[1024 + col];
        const float c_r = bhh[col], c_z = bhh[512 + col], c_n = bhh[1024 + col];
        const size_t cbase = (size_t)(col >> 3) * NB * 8 + (col & 7);
        #pragma unroll
        for (int mi = 0; mi < 4; ++mi) {
            #pragma unroll
            for (int j = 0; j < 4; ++j) {
                const int r = rowb + mi * 16 + j;
                const int word = wd[mi * 4 + j];
                float wir = 0.f, wiz = 0.f, win = 0.f;
                if (word >= 0) {
                    const float* wt = WihT + (size_t)word * 1536 + col;
                    wir = wt[0]; wiz = wt[512]; win = wt[1024];
                }
                const size_t idx = cbase + (size_t)r * 8;
                const float ra = wir + b_r + acc[0][mi][ni][j] + c_r;
                const float za = wiz + b_z + acc[1][mi][ni][j] + c_z;
                const float rr = PURE ? sigm_fast(ra) : sigm_mid(ra);
                const float zz = PURE ? sigm_fast(za) : sigm_mid(za);
                const float na = win + b_n + rr * (acc[2][mi][ni][j] + c_n);
                const float nn = PURE ? tanh_fast(na) : tanh_mid(na);
                const float hv = (1.f - zz) * nn + zz * hold[ni][mi][j];
                const f16 hh = (f16)hv;
                hn_hi[idx] = hh;
                if (!PURE) hn_lo[idx] = (f16)(hv - (float)hh);
            }
        }
    }
}

// ---------------- logits+gumbel argmax via split-fp16 MFMA (full NB, single h buffer) ----------------
__global__ __launch_bounds__(256, 2) void argmax_mfma(
    const f16* __restrict__ h_hi, const f16* __restrict__ h_lo,
    const f16* __restrict__ wsp_hi, const f16* __restrict__ wsp_lo,
    const float* __restrict__ bsp, const float* __restrict__ gum,
    int* __restrict__ wout)
{
    __shared__ __align__(16) f16 lds[2 * 1536 * 8];
    const int t = threadIdx.x;
    const int lane = t & 63, wave = t >> 6;
    const int mBase = blockIdx.x * 64;

    const f32x4 z4 = {0.f, 0.f, 0.f, 0.f};
    f32x4 acc[8];
    #pragma unroll
    for (int nf = 0; nf < 8; ++nf) acc[nf] = z4;

    const f16* sp[6];
    sp[0] = h_hi   + ((size_t)(t >> 6) * NB + mBase + (t & 63)) * 8;
    sp[1] = h_lo   + ((size_t)(t >> 6) * NB + mBase + (t & 63)) * 8;
    sp[2] = wsp_hi + ((size_t)(t >> 7) * 128 + (t & 127)) * 8;
    sp[3] = wsp_hi + ((size_t)(2 + (t >> 7)) * 128 + (t & 127)) * 8;
    sp[4] = wsp_lo + ((size_t)(t >> 7) * 128 + (t & 127)) * 8;
    sp[5] = wsp_lo + ((size_t)(2 + (t >> 7)) * 128 + (t & 127)) * 8;

    f16x8 st[6];
    #pragma unroll
    for (int i = 0; i < 6; ++i) {
        st[i] = *(const f16x8*)sp[i];
        sp[i] += (i < 2) ? (size_t)NB * 32 : (size_t)4096;
    }

    const int aselU = (lane >> 4) * 64 + wave * 16 + (lane & 15);
    const int bselU = 512 + (lane >> 4) * 128 + (lane & 15);

    for (int kb = 0; kb < 16; ++kb) {
        f16* lb = lds + (size_t)(kb & 1) * 1536 * 8;
        #pragma unroll
        for (int i = 0; i < 6; ++i)
            *(f16x8*)&lb[(size_t)(i * 256 + t) * 8] = st[i];
        __syncthreads();
        if (kb < 15) {
            #pragma unroll
            for (int i = 0; i < 6; ++i) {
                st[i] = *(const f16x8*)sp[i];
                sp[i] += (i < 2) ? (size_t)NB * 32 : (size_t)4096;
            }
        }

        f16x8 ah = *(const f16x8*)&lb[(size_t)aselU * 8];
        f16x8 al = *(const f16x8*)&lb[(size_t)(256 + aselU) * 8];
        #pragma unroll
        for (int nf = 0; nf < 8; ++nf) {
            f16x8 bh = *(const f16x8*)&lb[(size_t)(bselU + nf * 16) * 8];
            f16x8 bl = *(const f16x8*)&lb[(size_t)(512 + bselU + nf * 16) * 8];
            acc[nf] = __builtin_amdgcn_mfma_f32_16x16x32_f16(ah, bh, acc[nf], 0, 0, 0);
            acc[nf] = __builtin_amdgcn_mfma_f32_16x16x32_f16(ah, bl, acc[nf], 0, 0, 0);
            acc[nf] = __builtin_amdgcn_mfma_f32_16x16x32_f16(al, bh, acc[nf], 0, 0, 0);
        }
    }

    float bv[4];
    int bi[4];
    #pragma unroll
    for (int j = 0; j < 4; ++j) { bv[j] = -1e30f; bi[j] = 0; }
    const int rw0 = mBase + wave * 16 + ((lane >> 4) << 2);
    #pragma unroll
    for (int nf = 0; nf < 8; ++nf) {
        const int col = (lane & 15) + nf * 16;
        const float bb = bsp[col];
        #pragma unroll
        for (int j = 0; j < 4; ++j) {
            const float v = acc[nf][j] + bb + gum[(size_t)(rw0 + j) * 128 + col];
            if (v > bv[j] || (v == bv[j] && col < bi[j])) { bv[j] = v; bi[j] = col; }
        }
    }
    #pragma unroll
    for (int j = 0; j < 4; ++j) {
        #pragma unroll
        for (int off = 1; off <= 8; off <<= 1) {
            const float ov = __shfl_xor(bv[j], off, 64);
            const int oi = __shfl_xor(bi[j], off, 64);
            if (ov > bv[j] || (ov == bv[j] && oi < bi[j])) { bv[j] = ov; bi[j] = oi; }
        }
        if ((lane & 15) == 0) wout[rw0 + j] = bi[j];
    }
}

// ---------------- alive mask -> effective word (-1 = zero input) ----------------
__global__ __launch_bounds__(256) void eff_kernel(
    const int* __restrict__ words, int* __restrict__ eff)
{
    const int b = blockIdx.x * 256 + threadIdx.x;
    int alive = 1;
    #pragma unroll
    for (int t = 0; t < NT; ++t) {
        const int w = words[(size_t)t * NB + b];
        eff[(size_t)t * NB + b] = alive ? w : -1;
        alive = alive & (w != 0);
    }
}

// ---------------- score = [h_n, task] @ W_c^T + b_c (full NB, hi-only state) ----------------
__global__ __launch_bounds__(256) void score_kernel(
    const f16* __restrict__ h_hi,
    const float* __restrict__ x, const float* __restrict__ Wc,
    const float* __restrict__ bc, float* __restrict__ out)
{
    __shared__ float Wcs[10][528];
    const int t = threadIdx.x;
    for (int q = t; q < 1320; q += 256)
        *(float4*)&(((float*)Wcs)[q * 4]) = *(const float4*)&Wc[q * 4];
    __syncthreads();

    const int row = blockIdx.x * 256 + t;
    float acc[10];
    #pragma unroll
    for (int d = 0; d < 10; ++d) acc[d] = 0.f;

    for (int kg = 0; kg < 64; ++kg) {
        f16x8 vh = *(const f16x8*)&h_hi[((size_t)kg * NB + row) * 8];
        #pragma unroll
        for (int i = 0; i < 8; ++i) {
            const float v = (float)vh[i];
            #pragma unroll
            for (int d = 0; d < 10; ++d) acc[d] += v * Wcs[d][kg * 8 + i];
        }
    }
    #pragma unroll
    for (int j = 0; j < 16; ++j) {
        const float tv = x[(size_t)row * 272 + j];
        #pragma unroll
        for (int d = 0; d < 10; ++d) acc[d] += tv * Wcs[d][512 + j];
    }
    #pragma unroll
    for (int d = 0; d < 10; ++d) out[(size_t)row * 10 + d] = acc[d] + bc[d];
}

extern "C" void kernel_launch(void* const* d_in, const int* in_sizes, int n_in,
                              void* d_out, int out_size, void* d_ws, size_t ws_size,
                              hipStream_t stream) {
    const float* x      = (const float*)d_in[0];
    const float* gumbel = (const float*)d_in[1];
    const float* W_in   = (const float*)d_in[2];
    const float* b_in   = (const float*)d_in[3];
    const float* Wih_s  = (const float*)d_in[4];
    const float* Whh_s  = (const float*)d_in[5];
    const float* bih_s  = (const float*)d_in[6];
    const float* bhh_s  = (const float*)d_in[7];
    const float* W_sp   = (const float*)d_in[8];
    const float* b_sp   = (const float*)d_in[9];
    const float* Wih_r  = (const float*)d_in[10];
    const float* Whh_r  = (const float*)d_in[11];
    const float* bih_r  = (const float*)d_in[12];
    const float* bhh_r  = (const float*)d_in[13];
    const float* W_c    = (const float*)d_in[14];
    const float* b_c    = (const float*)d_in[15];
    float* out = (float*)d_out;

    // workspace map (bytes), total ~94 MB (ws = 320 MiB per harness poison fill)
    char* base = (char*)d_ws;
    f16* S_hi[2], *S_lo[2];
    S_hi[0] = (f16*)(base);
    S_lo[0] = (f16*)(base + 16777216);
    S_hi[1] = (f16*)(base + 33554432);
    S_lo[1] = (f16*)(base + 50331648);
    f16* R0 = (f16*)(base);
    f16* R1 = (f16*)(base + 16777216);
    f16* ws_s_hi = (f16*)(base + 67108864);
    f16* ws_s_lo = (f16*)(base + 68681728);
    f16* ws_r_hi = (f16*)(base + 70254592);
    f16* ws_r_lo = (f16*)(base + 71827456);
    float* wihT_s = (float*)(base + 73400320);
    float* wihT_r = (float*)(base + 74186752);
    int* words   = (int*)(base + 74973184);
    int* eff     = (int*)(base + 75628544);
    f16* wsp_hi  = (f16*)(base + 76283904);
    f16* wsp_lo  = (f16*)(base + 76414976);
    f16* xs_hi   = (f16*)(base + 76546048);
    f16* xs_lo   = (f16*)(base + 84934656);
    f16* win_hi  = (f16*)(base + 93323264);
    f16* win_lo  = (f16*)(base + 93585408);

    const dim3 blk(256);
    const dim3 gFus(NB / 128 * 8);    // 1024 blocks, 1-D, XCD-swizzled in-kernel

    // ---- weight/input prep ----
    wsplit_kernel<<<dim3(384), blk, 0, stream>>>(Whh_s, ws_s_hi, ws_s_lo, 1536, 512);
    wsplit_kernel<<<dim3(384), blk, 0, stream>>>(Whh_r, ws_r_hi, ws_r_lo, 1536, 512);
    wsplit_kernel<<<dim3(32), blk, 0, stream>>>(W_sp, wsp_hi, wsp_lo, 128, 512);
    wsplit_kernel<<<dim3(64), blk, 0, stream>>>(W_in, win_hi, win_lo, 512, 256);
    xsplit_kernel<<<dim3(2048), blk, 0, stream>>>(x, xs_hi, xs_lo);
    wihT_kernel<<<dim3(768), blk, 0, stream>>>(Wih_s, wihT_s);
    wihT_kernel<<<dim3(768), blk, 0, stream>>>(Wih_r, wihT_r);

    // ---- h0 into S0 (full NB, split MFMA) ----
    h0_mfma<<<gFus, blk, 0, stream>>>(xs_hi, xs_lo, win_hi, win_lo, b_in, S_hi[0], S_lo[0]);
    int cur = 0;

    // ---- sender: 10 fused GRU steps (split, triple-product) + MFMA argmax ----
    for (int t = 0; t < NT; ++t) {
        const int* wprev = (t == 0) ? (const int*)nullptr : (words + (size_t)(t - 1) * NB);
        const int nxt = cur ^ 1;
        fused_gru<0, 0><<<gFus, blk, 0, stream>>>(
            S_hi[cur], S_lo[cur], S_hi[nxt], S_lo[nxt],
            ws_s_hi, ws_s_lo, wihT_s, bih_s, bhh_s, wprev);
        cur = nxt;
        argmax_mfma<<<dim3(NB / 64), blk, 0, stream>>>(
            S_hi[cur], S_lo[cur], wsp_hi, wsp_lo,
            b_sp, gumbel + (size_t)t * NB * 128, words + (size_t)t * NB);
    }
    eff_kernel<<<dim3(NB / 256), blk, 0, stream>>>(words, eff);

    // ---- receiver: 10 fused GRU steps, pure fp16 hi-only, full-NB ping-pong ----
    fused_gru<1, 1><<<gFus, blk, 0, stream>>>(
        R1, R1, R0, R0, ws_r_hi, ws_r_lo, wihT_r, bih_r, bhh_r, eff);
    for (int t = 1; t < NT; ++t) {
        f16* rin  = (t & 1) ? R0 : R1;
        f16* rout = (t & 1) ? R1 : R0;
        fused_gru<0, 1><<<gFus, blk, 0, stream>>>(
            rin, rin, rout, rout, ws_r_hi, ws_r_lo, wihT_r, bih_r, bhh_r,
            eff + (size_t)t * NB);
    }

    // ---- score (final receiver state in R1: t=9 is odd) ----
    score_kernel<<<dim3(NB / 256), blk, 0, stream>>>(R1, x, W_c, b_c, out);
}